// Round 8
// baseline (106.782 us; speedup 1.0000x reference)
//
#include <hip/hip_runtime.h>
#include <stdint.h>

// Problem dims (fixed by the reference's setup_inputs)
#define B    8
#define C    80
#define M    100
#define NPIX 16384          // 128*128
#define NT   16             // cells per block tile
#define BT   128            // threads per block (2 waves)
#define NW   4              // waves per block in init kernel (256 threads)

#define ALPHA_F 0.25f
#define EPS_F   1e-8f

// Order-preserving float -> uint32 map (total order; no NaNs expected here).
__device__ __forceinline__ uint32_t fkey(float f) {
    uint32_t u = __float_as_uint(f);
    return (u & 0x80000000u) ? ~u : (u | 0x80000000u);
}

// ---------------------------------------------------------------------------
// init: one wave per (b,m). cid = first argmax of one-hot row; keys = +inf.
// ---------------------------------------------------------------------------
__global__ __launch_bounds__(256) void init_kernel(
    const float* __restrict__ cls_true,   // (B*M, C)
    int* __restrict__ cids,
    unsigned long long* __restrict__ keys)
{
    const int bm   = blockIdx.x * NW + (threadIdx.x >> 6);
    const int lane = threadIdx.x & 63;
    if (bm >= B * M) return;

    const float* ct = cls_true + (size_t)bm * C;
    // key = (fkey(v) << 32) | (C-1-c): max over keys -> max v, tie -> min c
    const float v0 = ct[lane];
    unsigned long long k =
        ((unsigned long long)fkey(v0) << 32) | (unsigned int)(C - 1 - lane);
    if (lane + 64 < C) {
        const float v1 = ct[lane + 64];
        unsigned long long k1 =
            ((unsigned long long)fkey(v1) << 32) | (unsigned int)(C - 1 - (lane + 64));
        if (k1 > k) k = k1;
    }
    #pragma unroll
    for (int off = 32; off > 0; off >>= 1) {
        unsigned long long o = __shfl_xor(k, off, 64);
        if (o > k) k = o;
    }
    if (lane == 0) {
        cids[bm] = C - 1 - (int)(k & 0xFFFFFFFFull);
        keys[bm] = 0xFFFFFFFFFFFFFFFFull;
    }
}

// ---------------------------------------------------------------------------
// fused match: block = (16-cell tile, b), 128 threads, lane-owns-m, uniform
// control flow. D stored [n][c] so the per-pair gather is ds_read_b32 at a
// fixed per-lane base (cid*4) + compile-time offset j*320 -- no addr VALU.
// Box data read per-j as wave-uniform float4 from loc_pred (scalar-friendly).
// 5.1 KB LDS -> residency capped by max-waves (32/CU); grid = 32 blocks/CU.
// One packed-key atomicMin per active lane per block.
// ---------------------------------------------------------------------------
__global__ __launch_bounds__(BT) void match_kernel(
    const float* __restrict__ cls_pred,   // (B, NPIX, C)
    const float* __restrict__ loc_pred,   // (B, NPIX, 4)
    const float* __restrict__ loc_true,   // (B, M, 4)
    const int*   __restrict__ cids,       // (B*M)
    unsigned long long* __restrict__ keys)// (B*M)
{
#pragma clang fp contract(off)
    __shared__ float D[NT][C];            // 5,120 B, [cell][class]

    const int b    = blockIdx.y;
    const int n0   = blockIdx.x * NT;
    const int tid  = threadIdx.x;
    const int lane = tid & 63;
    const int w    = tid >> 6;

    // ---- stage focal class-cost tile: float2 global loads, [n][c] LDS ----
    const float2* src2 = (const float2*)(cls_pred + ((size_t)b * NPIX + n0) * C);
    #pragma unroll
    for (int it = 0; it < NT * C / 2 / BT; ++it) {   // 5 iters
        const int idx2 = it * BT + tid;               // 0..639
        const int n    = idx2 / 40;                   // 40 float2 per cell
        const int c0   = (idx2 - n * 40) * 2;
        const float2 v = src2[idx2];
        const float pv[2] = { v.x, v.y };
        float fo[2];
        #pragma unroll
        for (int jj = 0; jj < 2; ++jj) {
            const float p = pv[jj];
            const float q = 1.0f - p;
            const float pos = (ALPHA_F * (q * q)) * (-logf(p + EPS_F));
            const float neg = ((1.0f - ALPHA_F) * (p * p)) * (-logf(q + EPS_F));
            fo[jj] = pos - neg;
        }
        *(float2*)&D[n][c0] = make_float2(fo[0], fo[1]);  // ds_write_b64
    }

    // ---- per-lane target (m) data; clamp inactive lanes to m=0 (junk ok) ----
    const int  mm  = w * 64 + lane;
    const int  bm  = b * M + (mm < M ? mm : 0);
    const int  cid = cids[bm];
    const float4 lt = *(const float4*)(loc_true + (size_t)bm * 4);
    const float ty1 = lt.x, tx1 = lt.y, ty2 = lt.z, tx2 = lt.w;
    const float t_area = fmaxf(ty2 - ty1, 0.0f) * fmaxf(tx2 - tx1, 0.0f);

    __syncthreads();

    // ---- scan: lane owns m, serial over 16 cells; boxes wave-uniform ----
    const float4* lp4 = (const float4*)loc_pred + ((size_t)b * NPIX + n0);
    const float inv = 1.0f / 128.0f;

    float bestv = __builtin_huge_valf();
    int   bestn = 0;

    #pragma unroll
    for (int j = 0; j < NT; ++j) {
        const float4 lp = lp4[j];                    // wave-uniform load
        const float py1 = lp.x * inv;
        const float px1 = lp.y * inv;
        const float py2 = lp.z * inv;
        const float px2 = lp.w * inv;
        const float pa  = fmaxf(py2 - py1, 0.0f) * fmaxf(px2 - px1, 0.0f);

        const float d = D[j][cid];                   // ds_read_b32, imm offset

        // reg: sum(|loc_true - loc_p|), left-assoc like np
        const float r = ((fabsf(ty1 - py1) + fabsf(tx1 - px1))
                         + fabsf(ty2 - py2)) + fabsf(tx2 - px2);

        // giou
        const float ih = fmaxf(fminf(py2, ty2) - fmaxf(py1, ty1), 0.0f);
        const float iw = fmaxf(fminf(px2, tx2) - fmaxf(px1, tx1), 0.0f);
        const float inter = ih * iw;
        const float uni   = (pa + t_area) - inter;
        const float iou   = (uni > 0.0f) ? (inter / fmaxf(uni, EPS_F)) : 0.0f;
        const float eh = fmaxf(py2, ty2) - fminf(py1, ty1);
        const float ew = fmaxf(px2, tx2) - fminf(px1, tx1);
        const float enc = eh * ew;
        const float pen = (enc > 0.0f) ? ((enc - uni) / fmaxf(enc, EPS_F)) : 0.0f;
        const float gl  = 1.0f - (iou - pen);

        const float total = ((2.0f * d) + (5.0f * r)) + (2.0f * gl);

        if (total < bestv) { bestv = total; bestn = n0 + j; }  // strict < => first index
    }

    if (mm < M) {
        const unsigned long long key =
            ((unsigned long long)fkey(bestv) << 32) | (unsigned int)bestn;
        atomicMin(&keys[bm], key);
    }
}

// ---------------------------------------------------------------------------
// writeout: unpack to (b, argmin, cid) int32
// ---------------------------------------------------------------------------
__global__ void write_out_kernel(const unsigned long long* __restrict__ keys,
                                 const int* __restrict__ cids,
                                 int* __restrict__ out) {
    int i = blockIdx.x * blockDim.x + threadIdx.x;
    if (i >= B * M) return;
    out[i * 3 + 0] = i / M;
    out[i * 3 + 1] = (int)(keys[i] & 0xFFFFFFFFull);
    out[i * 3 + 2] = cids[i];
}

// ===========================================================================
extern "C" void kernel_launch(void* const* d_in, const int* in_sizes, int n_in,
                              void* d_out, int out_size, void* d_ws, size_t ws_size,
                              hipStream_t stream) {
    const float* cls_pred = (const float*)d_in[0];
    const float* loc_pred = (const float*)d_in[1];
    const float* cls_true = (const float*)d_in[2];
    const float* loc_true = (const float*)d_in[3];
    int* out = (int*)d_out;

    unsigned long long* keys = (unsigned long long*)d_ws;
    int* cids = (int*)((char*)d_ws + (size_t)B * M * sizeof(unsigned long long));

    init_kernel<<<(B * M + NW - 1) / NW, 256, 0, stream>>>(cls_true, cids, keys);
    match_kernel<<<dim3(NPIX / NT, B), BT, 0, stream>>>(
        cls_pred, loc_pred, loc_true, cids, keys);
    write_out_kernel<<<(B * M + 255) / 256, 256, 0, stream>>>(keys, cids, out);
}

// Round 9
// 65.841 us; speedup vs baseline: 1.6218x; 1.6218x over previous
//
#include <hip/hip_runtime.h>
#include <stdint.h>

// Problem dims (fixed by the reference's setup_inputs)
#define B    8
#define C    80
#define M    100
#define NPIX 16384          // 128*128
#define NT   128            // cells per block tile
#define BT   256            // threads per block (4 waves)
#define NW   4              // waves per block in init kernel (256 threads)

#define ALPHA_F 0.25f
#define EPS_F   1e-8f

// Bank swizzle for class rows: spreads per-cid gathers across banks
#define SWZ(c) ((((c) & 31)) ^ ((((c) >> 5)) << 3))

// Order-preserving float -> uint32 map (total order; no NaNs expected here).
__device__ __forceinline__ uint32_t fkey(float f) {
    uint32_t u = __float_as_uint(f);
    return (u & 0x80000000u) ? ~u : (u | 0x80000000u);
}

// ---------------------------------------------------------------------------
// init: one wave per (b,m). cid = first argmax of one-hot row; keys = +inf.
// ---------------------------------------------------------------------------
__global__ __launch_bounds__(256) void init_kernel(
    const float* __restrict__ cls_true,   // (B*M, C)
    int* __restrict__ cids,
    unsigned long long* __restrict__ keys)
{
    const int bm   = blockIdx.x * NW + (threadIdx.x >> 6);
    const int lane = threadIdx.x & 63;
    if (bm >= B * M) return;

    const float* ct = cls_true + (size_t)bm * C;
    // key = (fkey(v) << 32) | (C-1-c): max over keys -> max v, tie -> min c
    const float v0 = ct[lane];
    unsigned long long k =
        ((unsigned long long)fkey(v0) << 32) | (unsigned int)(C - 1 - lane);
    if (lane + 64 < C) {
        const float v1 = ct[lane + 64];
        unsigned long long k1 =
            ((unsigned long long)fkey(v1) << 32) | (unsigned int)(C - 1 - (lane + 64));
        if (k1 > k) k = k1;
    }
    #pragma unroll
    for (int off = 32; off > 0; off >>= 1) {
        unsigned long long o = __shfl_xor(k, off, 64);
        if (o > k) k = o;
    }
    if (lane == 0) {
        cids[bm] = C - 1 - (int)(k & 0xFFFFFFFFull);
        keys[bm] = 0xFFFFFFFFFFFFFFFFull;
    }
}

// ---------------------------------------------------------------------------
// prep: pbox[b][n][8] = {py1,px1,py2,px2,p_area,0,0,0} (scaled), 32B/cell so
// the match kernel can read it with wave-uniform scalar loads.
// ---------------------------------------------------------------------------
__global__ __launch_bounds__(256) void prep_kernel(
    const float* __restrict__ loc_pred,   // (B, NPIX, 4)
    float* __restrict__ pbox)             // (B*NPIX, 8)
{
#pragma clang fp contract(off)
    const int i = blockIdx.x * 256 + threadIdx.x;
    if (i >= B * NPIX) return;
    const float inv = 1.0f / 128.0f;
    const float4 lp = ((const float4*)loc_pred)[i];
    const float py1 = lp.x * inv;
    const float px1 = lp.y * inv;
    const float py2 = lp.z * inv;
    const float px2 = lp.w * inv;
    const float pa  = fmaxf(py2 - py1, 0.0f) * fmaxf(px2 - px1, 0.0f);
    float4* dst = (float4*)pbox + (size_t)i * 2;
    dst[0] = make_float4(py1, px1, py2, px2);
    dst[1] = make_float4(pa, 0.0f, 0.0f, 0.0f);
}

// ---------------------------------------------------------------------------
// fused match: block = (128-cell tile, b), 256 threads (4 waves), lane-owns-m,
// uniform control flow. Waves {0,2} own m=lane and scan halves {0-63, 64-127};
// waves {1,3} own m=64+lane likewise. Focal costs staged fused into swizzled
// LDS [c][n^SWZ(c)] (40,960 B exactly -> 4 blocks/CU exact, grid = 4/CU
// exact, 16 waves/CU). Boxes via wave-uniform scalar loads from pbox. One
// packed-key atomicMin per active lane.
// ---------------------------------------------------------------------------
__global__ __launch_bounds__(BT) void match_kernel(
    const float* __restrict__ cls_pred,   // (B, NPIX, C)
    const float* __restrict__ pbox,       // (B*NPIX, 8)
    const float* __restrict__ loc_true,   // (B, M, 4)
    const int*   __restrict__ cids,       // (B*M)
    unsigned long long* __restrict__ keys)// (B*M)
{
#pragma clang fp contract(off)
    __shared__ float D[C * NT];           // 40,960 B, addr c*NT + (n ^ SWZ(c))

    const int b    = blockIdx.y;
    const int n0   = blockIdx.x * NT;
    const int tid  = threadIdx.x;
    const int lane = tid & 63;
    const int w    = tid >> 6;

    // ---- stage focal class-cost tile: float4 global loads, swizzled LDS ----
    const float4* src4 = (const float4*)(cls_pred + ((size_t)b * NPIX + n0) * C);
    #pragma unroll
    for (int it = 0; it < NT * C / 4 / BT; ++it) {   // 10 iters
        const int idx4 = it * BT + tid;
        const int n    = idx4 / 20;                   // 20 float4 per cell
        const int c0   = (idx4 - n * 20) * 4;
        const float4 v = src4[idx4];
        const float pv[4] = { v.x, v.y, v.z, v.w };
        #pragma unroll
        for (int jj = 0; jj < 4; ++jj) {
            const int c = c0 + jj;
            const float p = pv[jj];
            const float q = 1.0f - p;
            const float pos = (ALPHA_F * (q * q)) * (-logf(p + EPS_F));
            const float neg = ((1.0f - ALPHA_F) * (p * p)) * (-logf(q + EPS_F));
            D[c * NT + ((n ^ SWZ(c)) & (NT - 1))] = pos - neg;
        }
    }

    // ---- per-lane target (m); clamp inactive lanes to m=0 (junk, masked) ----
    const int  mm  = (w & 1) * 64 + lane;
    const int  bm  = b * M + (mm < M ? mm : 0);
    const int  cid = cids[bm];
    const float4 lt = *(const float4*)(loc_true + (size_t)bm * 4);
    const float ty1 = lt.x, tx1 = lt.y, ty2 = lt.z, tx2 = lt.w;
    const float t_area = fmaxf(ty2 - ty1, 0.0f) * fmaxf(tx2 - tx1, 0.0f);
    const int drow = cid * NT;
    const int sw   = SWZ(cid);

    __syncthreads();

    // ---- scan: lane owns m, serial over this wave's 64-cell half ----
    const int jbase = (w >> 1) * 64;
    const float* pb = pbox + ((size_t)(b * NPIX) + n0 + jbase) * 8;

    float bestv = __builtin_huge_valf();
    int   bestn = 0;

    #pragma unroll 8
    for (int j = 0; j < 64; ++j) {
        const int cell = jbase + j;
        const float d   = D[drow + (cell ^ sw)];     // per-lane LDS gather
        const float py1 = pb[j * 8 + 0];             // wave-uniform -> s_load
        const float px1 = pb[j * 8 + 1];
        const float py2 = pb[j * 8 + 2];
        const float px2 = pb[j * 8 + 3];
        const float pa  = pb[j * 8 + 4];

        // reg: sum(|loc_true - loc_p|), left-assoc like np
        const float r = ((fabsf(ty1 - py1) + fabsf(tx1 - px1))
                         + fabsf(ty2 - py2)) + fabsf(tx2 - px2);

        // giou
        const float ih = fmaxf(fminf(py2, ty2) - fmaxf(py1, ty1), 0.0f);
        const float iw = fmaxf(fminf(px2, tx2) - fmaxf(px1, tx1), 0.0f);
        const float inter = ih * iw;
        const float uni   = (pa + t_area) - inter;
        const float iou   = (uni > 0.0f) ? (inter / fmaxf(uni, EPS_F)) : 0.0f;
        const float eh = fmaxf(py2, ty2) - fminf(py1, ty1);
        const float ew = fmaxf(px2, tx2) - fminf(px1, tx1);
        const float enc = eh * ew;
        const float pen = (enc > 0.0f) ? ((enc - uni) / fmaxf(enc, EPS_F)) : 0.0f;
        const float gl  = 1.0f - (iou - pen);

        const float total = ((2.0f * d) + (5.0f * r)) + (2.0f * gl);

        if (total < bestv) { bestv = total; bestn = n0 + cell; }  // strict < => first index
    }

    if (mm < M) {
        const unsigned long long key =
            ((unsigned long long)fkey(bestv) << 32) | (unsigned int)bestn;
        atomicMin(&keys[bm], key);
    }
}

// ---------------------------------------------------------------------------
// writeout: unpack to (b, argmin, cid) int32
// ---------------------------------------------------------------------------
__global__ void write_out_kernel(const unsigned long long* __restrict__ keys,
                                 const int* __restrict__ cids,
                                 int* __restrict__ out) {
    int i = blockIdx.x * blockDim.x + threadIdx.x;
    if (i >= B * M) return;
    out[i * 3 + 0] = i / M;
    out[i * 3 + 1] = (int)(keys[i] & 0xFFFFFFFFull);
    out[i * 3 + 2] = cids[i];
}

// ===========================================================================
extern "C" void kernel_launch(void* const* d_in, const int* in_sizes, int n_in,
                              void* d_out, int out_size, void* d_ws, size_t ws_size,
                              hipStream_t stream) {
    const float* cls_pred = (const float*)d_in[0];
    const float* loc_pred = (const float*)d_in[1];
    const float* cls_true = (const float*)d_in[2];
    const float* loc_true = (const float*)d_in[3];
    int* out = (int*)d_out;

    // ws layout: keys (6400 B) | cids (3200 B) | pad | pbox (4 MB, 32B-aligned)
    unsigned long long* keys = (unsigned long long*)d_ws;
    int*   cids = (int*)((char*)d_ws + (size_t)B * M * sizeof(unsigned long long));
    float* pbox = (float*)((char*)d_ws + 16384);

    init_kernel<<<(B * M + NW - 1) / NW, 256, 0, stream>>>(cls_true, cids, keys);
    prep_kernel<<<(B * NPIX + 255) / 256, 256, 0, stream>>>(loc_pred, pbox);
    match_kernel<<<dim3(NPIX / NT, B), BT, 0, stream>>>(
        cls_pred, pbox, loc_true, cids, keys);
    write_out_kernel<<<(B * M + 255) / 256, 256, 0, stream>>>(keys, cids, out);
}